// Round 1
// baseline (11388.846 us; speedup 1.0000x reference)
//
#include <hip/hip_runtime.h>

// ---------------- problem constants ----------------
#define TT 100
#define HH 256
#define NSTEP 8
__device__ __constant__ float kDT_SC = 1.0f / 24.0f;
#define HS (0.125f)          // 1/NSTEP

// ---------------- d_ws layout (floats) ----------------
#define OFF_WHH1T4   0         // [64][256][4]
#define OFF_WIH1T    65536     // [20][256]
#define OFF_WIH2AT   70656     // [8][256]
#define OFF_WIH2BT4  72704     // [64][256][4]
#define OFF_WHH2T4   138240    // [64][256][4]
#define OFF_OW1T4    203776    // [64][256][4]
#define OFF_IW1T4    269312    // [64][256][4]
#define OFF_FW1T4    334848    // [64][52][4]
#define OFF_FW2T4    348160    // [13][256][4]
#define OFF_B1C      361472    // [256] bih1+bhh1
#define OFF_B2C      361728    // [256] bih2+bhh2
#define WS_FLOATS    361984

// ---------------- LDS layout (floats) ----------------
#define L_FW1   0        // 13312
#define L_FW2   13312    // 13312
#define L_YCUR  26624    // 4 rows * 272 (4 chunks of 68 = 64 data + 4 pad)
#define L_Z     27712    // 4 * 64
#define L_HC2   27968    // 2 * 256
#define L_XA    28480    // 2 * 28
#define L_TR    28536    // 2
#define L_RED   28538    // 16
#define L_TOTAL 28554
#define LDS_BYTES (L_TOTAL * 4)

__device__ __forceinline__ float fast_tanh(float v) {
    float e = __expf(2.0f * v);
    return 1.0f - 2.0f / (e + 1.0f);
}
__device__ __forceinline__ void fma4(float4& a, const float4 w, const float4 h) {
    a.x = fmaf(w.x, h.x, a.x); a.y = fmaf(w.y, h.y, a.y);
    a.z = fmaf(w.z, h.z, a.z); a.w = fmaf(w.w, h.w, a.w);
}
__device__ __forceinline__ float rsum4(const float4 a) { return (a.x + a.y) + (a.z + a.w); }
// padded ycur indexing: row v has 4 chunks of 68 floats (64 valid + 4 pad)
__device__ __forceinline__ int yoffF(int v, int j) { return v * 272 + (j >> 6) * 68 + (j & 63); }
__device__ __forceinline__ int yoff4(int v, int jb) { return v * 68 + (jb >> 4) * 17 + (jb & 15); }

// ================= setup: repack weights into d_ws =================
__global__ void codernn_setup(const float* __restrict__ Wih1, const float* __restrict__ Whh1,
                              const float* __restrict__ bih1, const float* __restrict__ bhh1,
                              const float* __restrict__ Wih2, const float* __restrict__ Whh2,
                              const float* __restrict__ bih2, const float* __restrict__ bhh2,
                              const float* __restrict__ oW1, const float* __restrict__ iW1,
                              const float* __restrict__ fW1, const float* __restrict__ fW2,
                              float* __restrict__ ws) {
    int e = blockIdx.x * 256 + threadIdx.x;
    if (e >= WS_FLOATS) return;
    float v;
    if (e < OFF_WIH1T) {                 // Whh1T4
        int q = e; int jb = q >> 10, i = (q >> 2) & 255, dj = q & 3;
        v = Whh1[i * 256 + jb * 4 + dj];
    } else if (e < OFF_WIH2AT) {         // Wih1T [20][256]
        int q = e - OFF_WIH1T; int j = q >> 8, i = q & 255;
        v = (j < 19) ? Wih1[i * 19 + j] : 0.0f;
    } else if (e < OFF_WIH2BT4) {        // Wih2aT [8][256] (insulin cols 0..4)
        int q = e - OFF_WIH2AT; int j = q >> 8, i = q & 255;
        v = (j < 5) ? Wih2[i * 261 + j] : 0.0f;
    } else if (e < OFF_WHH2T4) {         // Wih2bT4 (cols 5..260)
        int q = e - OFF_WIH2BT4; int jb = q >> 10, i = (q >> 2) & 255, dj = q & 3;
        v = Wih2[i * 261 + 5 + jb * 4 + dj];
    } else if (e < OFF_OW1T4) {          // Whh2T4
        int q = e - OFF_WHH2T4; int jb = q >> 10, i = (q >> 2) & 255, dj = q & 3;
        v = Whh2[i * 256 + jb * 4 + dj];
    } else if (e < OFF_IW1T4) {          // oW1T4
        int q = e - OFF_OW1T4; int jb = q >> 10, i = (q >> 2) & 255, dj = q & 3;
        v = oW1[i * 256 + jb * 4 + dj];
    } else if (e < OFF_FW1T4) {          // iW1T4
        int q = e - OFF_IW1T4; int jb = q >> 10, i = (q >> 2) & 255, dj = q & 3;
        v = iW1[i * 256 + jb * 4 + dj];
    } else if (e < OFF_FW2T4) {          // fW1T4 [64][52][4]: (jb*52+k)*4+dj = fW1[k][4jb+dj]
        int q = e - OFF_FW1T4; int jb = q / 208; int r = q - jb * 208; int k = r >> 2, dj = r & 3;
        v = (k < 50) ? fW1[k * 256 + jb * 4 + dj] : 0.0f;
    } else if (e < OFF_B1C) {            // fW2T4 [13][256][4]: (kb*256+i)*4+dk = fW2[i][4kb+dk]
        int q = e - OFF_FW2T4; int kb = q >> 10, i = (q >> 2) & 255, dk = q & 3;
        int k = kb * 4 + dk;
        v = (k < 50) ? fW2[i * 50 + k] : 0.0f;
    } else if (e < OFF_B2C) {
        int q = e - OFF_B1C; v = bih1[q] + bhh1[q];
    } else {
        int q = e - OFF_B2C; v = bih2[q] + bhh2[q];
    }
    ws[e] = v;
}

// ================= main persistent kernel =================
__global__ __launch_bounds__(512, 2) void codernn_main(
    const float* __restrict__ dt, const float* __restrict__ x,
    const float* __restrict__ ws,
    const float* __restrict__ ob1, const float* __restrict__ oW2, const float* __restrict__ ob2,
    const float* __restrict__ ib1, const float* __restrict__ iW2, const float* __restrict__ ib2,
    const float* __restrict__ fb1, const float* __restrict__ fb2,
    float* __restrict__ out) {
    extern __shared__ float sm[];
    const int tid = threadIdx.x;
    const int b = tid >> 8;          // local batch (0/1)
    const int i = tid & 255;         // owned H component
    const int bg = blockIdx.x * 2 + b;
    const int lane = tid & 63, wv = tid >> 6;

    // stage f-net weights into LDS (fW1T4 ++ fW2T4 contiguous in ws)
    for (int idx = tid; idx < 26624; idx += 512) sm[idx] = ws[OFF_FW1T4 + idx];
    // zero h state (ycur rows, incl. pads)
    for (int idx = tid; idx < 1088; idx += 512) sm[L_YCUR + idx] = 0.0f;

    // per-thread constants
    const float b1ci = ws[OFF_B1C + i];
    const float b2ci = ws[OFF_B2C + i];
    const float ob1i = ob1[i], ib1i = ib1[i];
    const float oW2i = oW2[i], iW2i = iW2[i];
    const float fb2i = fb2[i];
    const float ob2s = ob2[0], ib2s = ib2[0];
    // z-phase role: vg selects state pair (0: cov b0/b1, 1: ins b0/b1)
    const int vg = tid >> 8, kz = (tid >> 2) & 63, p4 = tid & 3;
    const int kr = (kz < 52) ? kz : 51;                 // clamped into zero-pad rows
    const float fb1k = (kz < 50) ? fb1[kz] : 0.0f;

    const float4* Whh1T4  = (const float4*)(ws + OFF_WHH1T4);
    const float*  Wih1T   = ws + OFF_WIH1T;
    const float*  Wih2aT  = ws + OFF_WIH2AT;
    const float4* Wih2bT4 = (const float4*)(ws + OFF_WIH2BT4);
    const float4* Whh2T4  = (const float4*)(ws + OFF_WHH2T4);
    const float4* oW1T4   = (const float4*)(ws + OFF_OW1T4);
    const float4* iW1T4   = (const float4*)(ws + OFF_IW1T4);
    const float4* fW1T4   = (const float4*)(sm + L_FW1);
    const float4* fW2T4   = (const float4*)(sm + L_FW2);
    const float4* ycur4   = (const float4*)(sm + L_YCUR);
    const float4* z4      = (const float4*)(sm + L_Z);
    const float4* hc24    = (const float4*)(sm + L_HC2);

    const int yci = L_YCUR + yoffF(b, i);       // this thread's cov slot (floats)
    const int yii = L_YCUR + yoffF(2 + b, i);   // ins slot

    float hc_reg = 0.0f, hi_reg = 0.0f;
    __syncthreads();

    for (int t = 0; t < TT; ++t) {
        // ---- stage x and treat ----
        if (tid < 56) {
            int bb = tid / 28, c = tid - bb * 28;
            sm[L_XA + tid] = (c < 25) ? x[(blockIdx.x * 2 + bb) * (TT * 25) + t * 25 + c] : 0.0f;
        }
        if (i == 0) {
            const float* xp = x + bg * (TT * 25) + t * 25;
            sm[L_TR + b] = (xp[1] > 0.f || xp[2] > 0.f || xp[3] > 0.f || xp[4] > 0.f || xp[5] > 0.f) ? 1.0f : 0.0f;
        }
        const float scale = (dt[bg * (TT * 2) + t * 2 + 1] - dt[bg * (TT * 2) + t * 2]) * kDT_SC;
        __syncthreads();

        // ---- cell1: h_cov += tanh(xc@Wih1' + hc@Whh1' + b) ----
        {
            float acc = b1ci;
            acc = fmaf(Wih1T[i], sm[L_XA + b * 28 + 0], acc);
            #pragma unroll
            for (int j = 1; j < 19; ++j)
                acc = fmaf(Wih1T[j * 256 + i], sm[L_XA + b * 28 + 6 + j], acc);
            float4 a4 = {0.f, 0.f, 0.f, 0.f};
            #pragma unroll 8
            for (int jb = 0; jb < 64; ++jb) {
                float4 w = Whh1T4[jb * 256 + i];
                float4 h = ycur4[yoff4(b, jb)];
                fma4(a4, w, h);
            }
            acc += rsum4(a4);
            hc_reg = hc_reg + fast_tanh(acc);
            sm[L_HC2 + b * 256 + i] = hc_reg;
        }
        __syncthreads();

        // ---- cell2: h_ins += tanh([xi,hc_new]@Wih2' + hi@Whh2' + b) ----
        {
            float acc = b2ci;
            #pragma unroll
            for (int j = 0; j < 5; ++j)
                acc = fmaf(Wih2aT[j * 256 + i], sm[L_XA + b * 28 + 1 + j], acc);
            float4 a4 = {0.f, 0.f, 0.f, 0.f};
            #pragma unroll 8
            for (int jb = 0; jb < 64; ++jb) {
                float4 w = Wih2bT4[jb * 256 + i];
                float4 h = hc24[b * 64 + jb];
                fma4(a4, w, h);
            }
            #pragma unroll 8
            for (int jb = 0; jb < 64; ++jb) {
                float4 w = Whh2T4[jb * 256 + i];
                float4 h = ycur4[yoff4(2 + b, jb)];
                fma4(a4, w, h);
            }
            acc += rsum4(a4);
            hi_reg = hi_reg + fast_tanh(acc);
        }
        __syncthreads();
        // ODE init: publish both current states
        sm[yci] = hc_reg;
        sm[yii] = hi_reg;
        float y0c = hc_reg, y0i = hi_reg;

        // ---- ODE: 8 RK4 steps over 4 state vectors simultaneously ----
        for (int st = 0; st < NSTEP; ++st) {
            float accc = 0.f, acci = 0.f;
            #pragma unroll
            for (int e = 0; e < 4; ++e) {
                __syncthreads();   // ycur ready
                // z-phase: z[v][k] = tanh(fW1[k,:]·ycur[v] + fb1[k]), v = 2*vg+{0,1}
                float s0, s1;
                {
                    const float4* wp = fW1T4 + (p4 * 16) * 52 + kr;
                    const float4* ya = ycur4 + (2 * vg) * 68 + p4 * 17;
                    const float4* yb = ycur4 + (2 * vg + 1) * 68 + p4 * 17;
                    float4 a0 = {0.f,0.f,0.f,0.f}, a1 = {0.f,0.f,0.f,0.f};
                    #pragma unroll 4
                    for (int m = 0; m < 16; ++m) {
                        float4 w = wp[m * 52];
                        fma4(a0, w, ya[m]);
                        fma4(a1, w, yb[m]);
                    }
                    s0 = rsum4(a0); s1 = rsum4(a1);
                }
                s0 += __shfl_xor(s0, 1); s0 += __shfl_xor(s0, 2);
                s1 += __shfl_xor(s1, 1); s1 += __shfl_xor(s1, 2);
                if (p4 == 0) {
                    float z0 = 0.f, z1 = 0.f;
                    if (kz < 50) { z0 = fast_tanh(s0 + fb1k); z1 = fast_tanh(s1 + fb1k); }
                    sm[L_Z + (2 * vg) * 64 + kz] = z0;
                    sm[L_Z + (2 * vg + 1) * 64 + kz] = z1;
                }
                __syncthreads();   // z ready
                // update: du = (fW2·z + fb2) * scale, RK4 bookkeeping
                {
                    float4 dc4 = {0.f,0.f,0.f,0.f}, di4 = {0.f,0.f,0.f,0.f};
                    #pragma unroll 4
                    for (int kb = 0; kb < 13; ++kb) {
                        float4 w = fW2T4[kb * 256 + i];
                        fma4(dc4, w, z4[b * 16 + kb]);
                        fma4(di4, w, z4[(2 + b) * 16 + kb]);
                    }
                    float duc = (fb2i + rsum4(dc4)) * scale;
                    float dui = (fb2i + rsum4(di4)) * scale;
                    float yc, yi2;
                    if (e == 0) {
                        accc = duc; acci = dui;
                        yc = fmaf(0.5f * HS, duc, y0c); yi2 = fmaf(0.5f * HS, dui, y0i);
                    } else if (e == 1) {
                        accc = fmaf(2.f, duc, accc); acci = fmaf(2.f, dui, acci);
                        yc = fmaf(0.5f * HS, duc, y0c); yi2 = fmaf(0.5f * HS, dui, y0i);
                    } else if (e == 2) {
                        accc = fmaf(2.f, duc, accc); acci = fmaf(2.f, dui, acci);
                        yc = fmaf(HS, duc, y0c); yi2 = fmaf(HS, dui, y0i);
                    } else {
                        accc += duc; acci += dui;
                        y0c = fmaf(HS / 6.f, accc, y0c); y0i = fmaf(HS / 6.f, acci, y0i);
                        yc = y0c; yi2 = y0i;
                    }
                    sm[yci] = yc;
                    sm[yii] = yi2;
                }
            }
        }
        hc_reg = y0c; hi_reg = y0i;
        __syncthreads();   // final ycur (== h) visible

        // ---- output heads + reduction ----
        {
            float4 ao4 = {0.f,0.f,0.f,0.f}, ai4 = {0.f,0.f,0.f,0.f};
            #pragma unroll 8
            for (int jb = 0; jb < 64; ++jb) {
                float4 wo = oW1T4[jb * 256 + i];
                float4 hcv = ycur4[yoff4(b, jb)];
                fma4(ao4, wo, hcv);
                float4 wi = iW1T4[jb * 256 + i];
                float4 hiv = ycur4[yoff4(2 + b, jb)];
                fma4(ai4, wi, hiv);
            }
            float co = oW2i * fast_tanh(ob1i + rsum4(ao4));
            float ci = iW2i * fast_tanh(ib1i + rsum4(ai4));
            #pragma unroll
            for (int off = 32; off > 0; off >>= 1) {
                co += __shfl_xor(co, off);
                ci += __shfl_xor(ci, off);
            }
            if (lane == 0) { sm[L_RED + wv * 2] = co; sm[L_RED + wv * 2 + 1] = ci; }
        }
        __syncthreads();
        if (i == 0) {
            float sco = sm[L_RED + b * 8 + 0] + sm[L_RED + b * 8 + 2] + sm[L_RED + b * 8 + 4] + sm[L_RED + b * 8 + 6];
            float sci = sm[L_RED + b * 8 + 1] + sm[L_RED + b * 8 + 3] + sm[L_RED + b * 8 + 5] + sm[L_RED + b * 8 + 7];
            float muc = sco + ob2s;
            float mui = fmaxf(sci + ib2s, 0.0f);
            out[bg * TT + t] = muc - sm[L_TR + b] * mui;
        }
        __syncthreads();
    }
}

extern "C" void kernel_launch(void* const* d_in, const int* in_sizes, int n_in,
                              void* d_out, int out_size, void* d_ws, size_t ws_size,
                              hipStream_t stream) {
    const float* dt   = (const float*)d_in[0];
    const float* x    = (const float*)d_in[1];
    const float* Wih1 = (const float*)d_in[2];
    const float* Whh1 = (const float*)d_in[3];
    const float* bih1 = (const float*)d_in[4];
    const float* bhh1 = (const float*)d_in[5];
    const float* Wih2 = (const float*)d_in[6];
    const float* Whh2 = (const float*)d_in[7];
    const float* bih2 = (const float*)d_in[8];
    const float* bhh2 = (const float*)d_in[9];
    const float* oW1  = (const float*)d_in[10];
    const float* ob1  = (const float*)d_in[11];
    const float* oW2  = (const float*)d_in[12];
    const float* ob2  = (const float*)d_in[13];
    const float* iW1  = (const float*)d_in[14];
    const float* ib1  = (const float*)d_in[15];
    const float* iW2  = (const float*)d_in[16];
    const float* ib2  = (const float*)d_in[17];
    const float* fW1  = (const float*)d_in[18];
    const float* fb1  = (const float*)d_in[19];
    const float* fW2  = (const float*)d_in[20];
    const float* fb2  = (const float*)d_in[21];
    float* ws  = (float*)d_ws;
    float* out = (float*)d_out;

    if (ws_size < (size_t)WS_FLOATS * sizeof(float)) return;  // need ~1.45 MB scratch

    codernn_setup<<<WS_FLOATS / 256, 256, 0, stream>>>(Wih1, Whh1, bih1, bhh1, Wih2, Whh2,
                                                       bih2, bhh2, oW1, iW1, fW1, fW2, ws);

    (void)hipFuncSetAttribute((const void*)codernn_main,
                              hipFuncAttributeMaxDynamicSharedMemorySize, LDS_BYTES);
    codernn_main<<<256, 512, LDS_BYTES, stream>>>(dt, x, ws,
                                                  ob1, oW2, ob2, ib1, iW2, ib2, fb1, fb2, out);
}

// Round 2
// 8907.652 us; speedup vs baseline: 1.2785x; 1.2785x over previous
//
#include <hip/hip_runtime.h>

// ---------------- problem constants ----------------
#define TT 100
#define HH 256
#define NSTEP 8
__device__ __constant__ float kDT_SC = 1.0f / 24.0f;
#define HS (0.125f)          // 1/NSTEP

// ---------------- d_ws layout (floats) ----------------
#define OFF_WHH1T4   0         // [64][256][4]
#define OFF_WIH1T    65536     // [20][256]
#define OFF_WIH2AT   70656     // [8][256]
#define OFF_WIH2BT4  72704     // [64][256][4]
#define OFF_WHH2T4   138240    // [64][256][4]
#define OFF_OW1T4    203776    // [64][256][4]
#define OFF_IW1T4    269312    // [64][256][4]
#define OFF_FW1T4    334848    // [64][52][4]
#define OFF_FW2T4    348160    // [13][256][4]
#define OFF_B1C      361472    // [256] bih1+bhh1
#define OFF_B2C      361728    // [256] bih2+bhh2
#define WS_FLOATS    361984

// ---------------- LDS layout (floats) ----------------
#define L_YCUR  0        // 4 rows * 272 (4 chunks of 68 = 64 data + 4 pad)
#define L_Z     1088     // 4 * 64
#define L_HC2   1344     // 2 * 256
#define L_XA    1856     // 2 * 28
#define L_TR    1912     // 2
#define L_RED   1914     // 16
#define L_TOTAL 1930

__device__ __forceinline__ float fast_tanh(float v) {
    float e = __expf(2.0f * v);
    return 1.0f - 2.0f / (e + 1.0f);
}
__device__ __forceinline__ void fma4(float4& a, const float4 w, const float4 h) {
    a.x = fmaf(w.x, h.x, a.x); a.y = fmaf(w.y, h.y, a.y);
    a.z = fmaf(w.z, h.z, a.z); a.w = fmaf(w.w, h.w, a.w);
}
__device__ __forceinline__ float rsum4(const float4 a) { return (a.x + a.y) + (a.z + a.w); }
// padded ycur indexing: row v has 4 chunks of 68 floats (64 valid + 4 pad)
__device__ __forceinline__ int yoffF(int v, int j) { return v * 272 + (j >> 6) * 68 + (j & 63); }
__device__ __forceinline__ int yoff4(int v, int jb) { return v * 68 + (jb >> 4) * 17 + (jb & 15); }

// ================= setup: repack weights into d_ws =================
__global__ void codernn_setup(const float* __restrict__ Wih1, const float* __restrict__ Whh1,
                              const float* __restrict__ bih1, const float* __restrict__ bhh1,
                              const float* __restrict__ Wih2, const float* __restrict__ Whh2,
                              const float* __restrict__ bih2, const float* __restrict__ bhh2,
                              const float* __restrict__ oW1, const float* __restrict__ iW1,
                              const float* __restrict__ fW1, const float* __restrict__ fW2,
                              float* __restrict__ ws) {
    int e = blockIdx.x * 256 + threadIdx.x;
    if (e >= WS_FLOATS) return;
    float v;
    if (e < OFF_WIH1T) {                 // Whh1T4
        int q = e; int jb = q >> 10, i = (q >> 2) & 255, dj = q & 3;
        v = Whh1[i * 256 + jb * 4 + dj];
    } else if (e < OFF_WIH2AT) {         // Wih1T [20][256]
        int q = e - OFF_WIH1T; int j = q >> 8, i = q & 255;
        v = (j < 19) ? Wih1[i * 19 + j] : 0.0f;
    } else if (e < OFF_WIH2BT4) {        // Wih2aT [8][256] (insulin cols 0..4)
        int q = e - OFF_WIH2AT; int j = q >> 8, i = q & 255;
        v = (j < 5) ? Wih2[i * 261 + j] : 0.0f;
    } else if (e < OFF_WHH2T4) {         // Wih2bT4 (cols 5..260)
        int q = e - OFF_WIH2BT4; int jb = q >> 10, i = (q >> 2) & 255, dj = q & 3;
        v = Wih2[i * 261 + 5 + jb * 4 + dj];
    } else if (e < OFF_OW1T4) {          // Whh2T4
        int q = e - OFF_WHH2T4; int jb = q >> 10, i = (q >> 2) & 255, dj = q & 3;
        v = Whh2[i * 256 + jb * 4 + dj];
    } else if (e < OFF_IW1T4) {          // oW1T4
        int q = e - OFF_OW1T4; int jb = q >> 10, i = (q >> 2) & 255, dj = q & 3;
        v = oW1[i * 256 + jb * 4 + dj];
    } else if (e < OFF_FW1T4) {          // iW1T4
        int q = e - OFF_IW1T4; int jb = q >> 10, i = (q >> 2) & 255, dj = q & 3;
        v = iW1[i * 256 + jb * 4 + dj];
    } else if (e < OFF_FW2T4) {          // fW1T4 [64][52][4]: (jb*52+k)*4+dj = fW1[k][4jb+dj]
        int q = e - OFF_FW1T4; int jb = q / 208; int r = q - jb * 208; int k = r >> 2, dj = r & 3;
        v = (k < 50) ? fW1[k * 256 + jb * 4 + dj] : 0.0f;
    } else if (e < OFF_B1C) {            // fW2T4 [13][256][4]: (kb*256+i)*4+dk = fW2[i][4kb+dk]
        int q = e - OFF_FW2T4; int kb = q >> 10, i = (q >> 2) & 255, dk = q & 3;
        int k = kb * 4 + dk;
        v = (k < 50) ? fW2[i * 50 + k] : 0.0f;
    } else if (e < OFF_B2C) {
        int q = e - OFF_B1C; v = bih1[q] + bhh1[q];
    } else {
        int q = e - OFF_B2C; v = bih2[q] + bhh2[q];
    }
    ws[e] = v;
}

// ================= main persistent kernel =================
__global__ __launch_bounds__(512, 2) void codernn_main(
    const float* __restrict__ dt, const float* __restrict__ x,
    const float* __restrict__ ws,
    const float* __restrict__ ob1, const float* __restrict__ oW2, const float* __restrict__ ob2,
    const float* __restrict__ ib1, const float* __restrict__ iW2, const float* __restrict__ ib2,
    const float* __restrict__ fb1, const float* __restrict__ fb2,
    float* __restrict__ out) {
    __shared__ float sm[L_TOTAL];
    const int tid = threadIdx.x;
    const int b = tid >> 8;          // local batch (0/1)
    const int i = tid & 255;         // owned H component
    const int bg = blockIdx.x * 2 + b;
    const int lane = tid & 63, wv = tid >> 6;

    // zero h state (ycur rows, incl. pads)
    for (int idx = tid; idx < 1088; idx += 512) sm[L_YCUR + idx] = 0.0f;

    // per-thread constants
    const float b1ci = ws[OFF_B1C + i];
    const float b2ci = ws[OFF_B2C + i];
    const float ob1i = ob1[i], ib1i = ib1[i];
    const float oW2i = oW2[i], iW2i = iW2[i];
    const float fb2i = fb2[i];
    const float ob2s = ob2[0], ib2s = ib2[0];
    // z-phase role: vg selects state pair (0: cov b0/b1, 1: ins b0/b1)
    const int vg = tid >> 8, kz = (tid >> 2) & 63, p4 = tid & 3;
    const int kr = (kz < 52) ? kz : 51;                 // clamped into zero-pad rows
    const float fb1k = (kz < 50) ? fb1[kz] : 0.0f;

    const float4* Whh1T4  = (const float4*)(ws + OFF_WHH1T4);
    const float*  Wih1T   = ws + OFF_WIH1T;
    const float*  Wih2aT  = ws + OFF_WIH2AT;
    const float4* Wih2bT4 = (const float4*)(ws + OFF_WIH2BT4);
    const float4* Whh2T4  = (const float4*)(ws + OFF_WHH2T4);
    const float4* oW1T4   = (const float4*)(ws + OFF_OW1T4);
    const float4* iW1T4   = (const float4*)(ws + OFF_IW1T4);
    const float4* ycur4   = (const float4*)(sm + L_YCUR);
    const float4* z4      = (const float4*)(sm + L_Z);
    const float4* hc24    = (const float4*)(sm + L_HC2);

    // ---- register-cache the f-net weights (time-invariant) ----
    // z-phase slice: this lane's 64 columns of row kr -> 16 float4
    float4 wf1[16];
    {
        const float4* g = (const float4*)(ws + OFF_FW1T4);
        #pragma unroll
        for (int m = 0; m < 16; ++m) wf1[m] = g[(p4 * 16 + m) * 52 + kr];
    }
    // update-phase slice: row i of fW2 across 52 k -> 13 float4
    float4 wf2[13];
    {
        const float4* g = (const float4*)(ws + OFF_FW2T4);
        #pragma unroll
        for (int kb = 0; kb < 13; ++kb) wf2[kb] = g[kb * 256 + i];
    }

    const int yci = L_YCUR + yoffF(b, i);       // this thread's cov slot (floats)
    const int yii = L_YCUR + yoffF(2 + b, i);   // ins slot

    float hc_reg = 0.0f, hi_reg = 0.0f;
    __syncthreads();

    for (int t = 0; t < TT; ++t) {
        // ---- stage x and treat ----
        if (tid < 56) {
            int bb = tid / 28, c = tid - bb * 28;
            sm[L_XA + tid] = (c < 25) ? x[(blockIdx.x * 2 + bb) * (TT * 25) + t * 25 + c] : 0.0f;
        }
        if (i == 0) {
            const float* xp = x + bg * (TT * 25) + t * 25;
            sm[L_TR + b] = (xp[1] > 0.f || xp[2] > 0.f || xp[3] > 0.f || xp[4] > 0.f || xp[5] > 0.f) ? 1.0f : 0.0f;
        }
        const float scale = (dt[bg * (TT * 2) + t * 2 + 1] - dt[bg * (TT * 2) + t * 2]) * kDT_SC;
        __syncthreads();

        // ---- cell1: h_cov += tanh(xc@Wih1' + hc@Whh1' + b) ----
        {
            float acc = b1ci;
            acc = fmaf(Wih1T[i], sm[L_XA + b * 28 + 0], acc);
            #pragma unroll
            for (int j = 1; j < 19; ++j)
                acc = fmaf(Wih1T[j * 256 + i], sm[L_XA + b * 28 + 6 + j], acc);
            float4 a4 = {0.f, 0.f, 0.f, 0.f};
            #pragma unroll 8
            for (int jb = 0; jb < 64; ++jb) {
                float4 w = Whh1T4[jb * 256 + i];
                float4 h = ycur4[yoff4(b, jb)];
                fma4(a4, w, h);
            }
            acc += rsum4(a4);
            hc_reg = hc_reg + fast_tanh(acc);
            sm[L_HC2 + b * 256 + i] = hc_reg;
        }
        __syncthreads();

        // ---- cell2: h_ins += tanh([xi,hc_new]@Wih2' + hi@Whh2' + b) ----
        {
            float acc = b2ci;
            #pragma unroll
            for (int j = 0; j < 5; ++j)
                acc = fmaf(Wih2aT[j * 256 + i], sm[L_XA + b * 28 + 1 + j], acc);
            float4 a4 = {0.f, 0.f, 0.f, 0.f};
            #pragma unroll 8
            for (int jb = 0; jb < 64; ++jb) {
                float4 w = Wih2bT4[jb * 256 + i];
                float4 h = hc24[b * 64 + jb];
                fma4(a4, w, h);
            }
            #pragma unroll 8
            for (int jb = 0; jb < 64; ++jb) {
                float4 w = Whh2T4[jb * 256 + i];
                float4 h = ycur4[yoff4(2 + b, jb)];
                fma4(a4, w, h);
            }
            acc += rsum4(a4);
            hi_reg = hi_reg + fast_tanh(acc);
        }
        __syncthreads();
        // ODE init: publish both current states
        sm[yci] = hc_reg;
        sm[yii] = hi_reg;
        float y0c = hc_reg, y0i = hi_reg;

        // ---- ODE: 8 RK4 steps over 4 state vectors simultaneously ----
        for (int st = 0; st < NSTEP; ++st) {
            float accc = 0.f, acci = 0.f;
            #pragma unroll
            for (int e = 0; e < 4; ++e) {
                __syncthreads();   // ycur ready
                // z-phase: z[v][k] = tanh(fW1[k,:]·ycur[v] + fb1[k]), v = 2*vg+{0,1}
                float s0, s1;
                {
                    const float4* ya = ycur4 + (2 * vg) * 68 + p4 * 17;
                    const float4* yb = ya + 68;
                    float4 a0 = {0.f,0.f,0.f,0.f}, a1 = {0.f,0.f,0.f,0.f};
                    #pragma unroll
                    for (int m = 0; m < 16; ++m) {
                        fma4(a0, wf1[m], ya[m]);
                        fma4(a1, wf1[m], yb[m]);
                    }
                    s0 = rsum4(a0); s1 = rsum4(a1);
                }
                s0 += __shfl_xor(s0, 1); s0 += __shfl_xor(s0, 2);
                s1 += __shfl_xor(s1, 1); s1 += __shfl_xor(s1, 2);
                if (p4 == 0) {
                    float z0 = 0.f, z1 = 0.f;
                    if (kz < 50) { z0 = fast_tanh(s0 + fb1k); z1 = fast_tanh(s1 + fb1k); }
                    sm[L_Z + (2 * vg) * 64 + kz] = z0;
                    sm[L_Z + (2 * vg + 1) * 64 + kz] = z1;
                }
                __syncthreads();   // z ready
                // update: du = (fW2·z + fb2) * scale, RK4 bookkeeping
                {
                    float4 dc4 = {0.f,0.f,0.f,0.f}, di4 = {0.f,0.f,0.f,0.f};
                    #pragma unroll
                    for (int kb = 0; kb < 13; ++kb) {
                        fma4(dc4, wf2[kb], z4[b * 16 + kb]);
                        fma4(di4, wf2[kb], z4[(2 + b) * 16 + kb]);
                    }
                    float duc = (fb2i + rsum4(dc4)) * scale;
                    float dui = (fb2i + rsum4(di4)) * scale;
                    float yc, yi2;
                    if (e == 0) {
                        accc = duc; acci = dui;
                        yc = fmaf(0.5f * HS, duc, y0c); yi2 = fmaf(0.5f * HS, dui, y0i);
                    } else if (e == 1) {
                        accc = fmaf(2.f, duc, accc); acci = fmaf(2.f, dui, acci);
                        yc = fmaf(0.5f * HS, duc, y0c); yi2 = fmaf(0.5f * HS, dui, y0i);
                    } else if (e == 2) {
                        accc = fmaf(2.f, duc, accc); acci = fmaf(2.f, dui, acci);
                        yc = fmaf(HS, duc, y0c); yi2 = fmaf(HS, dui, y0i);
                    } else {
                        accc += duc; acci += dui;
                        y0c = fmaf(HS / 6.f, accc, y0c); y0i = fmaf(HS / 6.f, acci, y0i);
                        yc = y0c; yi2 = y0i;
                    }
                    sm[yci] = yc;
                    sm[yii] = yi2;
                }
            }
        }
        hc_reg = y0c; hi_reg = y0i;
        __syncthreads();   // final ycur (== h) visible

        // ---- output heads + reduction ----
        {
            float4 ao4 = {0.f,0.f,0.f,0.f}, ai4 = {0.f,0.f,0.f,0.f};
            #pragma unroll 8
            for (int jb = 0; jb < 64; ++jb) {
                float4 wo = oW1T4[jb * 256 + i];
                float4 hcv = ycur4[yoff4(b, jb)];
                fma4(ao4, wo, hcv);
                float4 wi = iW1T4[jb * 256 + i];
                float4 hiv = ycur4[yoff4(2 + b, jb)];
                fma4(ai4, wi, hiv);
            }
            float co = oW2i * fast_tanh(ob1i + rsum4(ao4));
            float ci = iW2i * fast_tanh(ib1i + rsum4(ai4));
            #pragma unroll
            for (int off = 32; off > 0; off >>= 1) {
                co += __shfl_xor(co, off);
                ci += __shfl_xor(ci, off);
            }
            if (lane == 0) { sm[L_RED + wv * 2] = co; sm[L_RED + wv * 2 + 1] = ci; }
        }
        __syncthreads();
        if (i == 0) {
            float sco = sm[L_RED + b * 8 + 0] + sm[L_RED + b * 8 + 2] + sm[L_RED + b * 8 + 4] + sm[L_RED + b * 8 + 6];
            float sci = sm[L_RED + b * 8 + 1] + sm[L_RED + b * 8 + 3] + sm[L_RED + b * 8 + 5] + sm[L_RED + b * 8 + 7];
            float muc = sco + ob2s;
            float mui = fmaxf(sci + ib2s, 0.0f);
            out[bg * TT + t] = muc - sm[L_TR + b] * mui;
        }
        __syncthreads();
    }
}

extern "C" void kernel_launch(void* const* d_in, const int* in_sizes, int n_in,
                              void* d_out, int out_size, void* d_ws, size_t ws_size,
                              hipStream_t stream) {
    const float* dt   = (const float*)d_in[0];
    const float* x    = (const float*)d_in[1];
    const float* Wih1 = (const float*)d_in[2];
    const float* Whh1 = (const float*)d_in[3];
    const float* bih1 = (const float*)d_in[4];
    const float* bhh1 = (const float*)d_in[5];
    const float* Wih2 = (const float*)d_in[6];
    const float* Whh2 = (const float*)d_in[7];
    const float* bih2 = (const float*)d_in[8];
    const float* bhh2 = (const float*)d_in[9];
    const float* oW1  = (const float*)d_in[10];
    const float* ob1  = (const float*)d_in[11];
    const float* oW2  = (const float*)d_in[12];
    const float* ob2  = (const float*)d_in[13];
    const float* iW1  = (const float*)d_in[14];
    const float* ib1  = (const float*)d_in[15];
    const float* iW2  = (const float*)d_in[16];
    const float* ib2  = (const float*)d_in[17];
    const float* fW1  = (const float*)d_in[18];
    const float* fb1  = (const float*)d_in[19];
    const float* fW2  = (const float*)d_in[20];
    const float* fb2  = (const float*)d_in[21];
    float* ws  = (float*)d_ws;
    float* out = (float*)d_out;

    if (ws_size < (size_t)WS_FLOATS * sizeof(float)) return;  // need ~1.45 MB scratch

    codernn_setup<<<WS_FLOATS / 256, 256, 0, stream>>>(Wih1, Whh1, bih1, bhh1, Wih2, Whh2,
                                                       bih2, bhh2, oW1, iW1, fW1, fW2, ws);

    codernn_main<<<256, 512, 0, stream>>>(dt, x, ws,
                                          ob1, oW2, ob2, ib1, iW2, ib2, fb1, fb2, out);
}